// Round 3
// baseline (5773.367 us; speedup 1.0000x reference)
//
#include <hip/hip_runtime.h>

// Problem constants
#define K_CB   8192
#define D_DIM  256
#define N_ROWS 32768
#define Q_ELEMS (N_ROWS * D_DIM)

// tiling
#define BM 64
#define BK 64
#define DC 32
#define WT_STRIDE 36     // 32+4 pad; 16B-aligned cols (144B), 2-way bank alias only (free)

// np-fp32 quantization bounds: per-score quantization error <= ulp(512)/2 * 2 rounds = 3.05e-5
// -> any np-winner has true score within 6.1e-5 of true min.
#define M_FLAG 7.2e-5f   // rows with margin above this are provably np-identical
#define M_CAND 6.6e-5f   // candidate window inside fixup
#define MAXC   24

// ws layout (bytes):
//   0       Wsq    [8192 f32]    (np w_sq; fp64-summed, fp32-rounded)
//   32768   Xsq    [32768 f32]
//   163840  rowmin [32768 f32]
//   294912  accum  f32
//   294916  flag_count u32
//   294920  flags  [32768 i32]

// fp32-rounded fp64 sum of squares per 256-float row
__global__ void sq_kernel(const float* __restrict__ m, float* __restrict__ out, int rows) {
    int wave = threadIdx.x >> 6, lane = threadIdx.x & 63;
    int row = blockIdx.x * 4 + wave;
    if (row >= rows) return;
    float4 v = reinterpret_cast<const float4*>(m)[(size_t)row * 64 + lane];
    double s = (double)v.x * v.x + (double)v.y * v.y + (double)v.z * v.z + (double)v.w * v.w;
    #pragma unroll
    for (int off = 32; off > 0; off >>= 1) s += __shfl_down(s, off, 64);
    if (lane == 0) out[row] = (float)s;
}

// Pass 1: fp32 GEMM argmin with (best, second-best); s = Wsq[k] - 2*dot
__global__ __launch_bounds__(256, 2) void argmin_kernel(
        const float* __restrict__ x, const float* __restrict__ w,
        const float* __restrict__ wsq, float* __restrict__ idx_out,
        float* __restrict__ rowmin,
        int* __restrict__ flags, unsigned* __restrict__ flag_count) {
    __shared__ float xs[BM * D_DIM];       // 64 KB
    __shared__ float wt[BK * WT_STRIDE];   // 9216 B

    const int t  = threadIdx.x;
    const int tx = t & 15;
    const int ty = t >> 4;
    const int r0 = blockIdx.x * BM;

    #pragma unroll
    for (int it = 0; it < 16; ++it) {
        int f = it * 256 + t, row = f >> 6, d4 = f & 63;
        reinterpret_cast<float4*>(xs)[row * 64 + d4] =
            reinterpret_cast<const float4*>(x)[(size_t)(r0 + row) * 64 + d4];
    }

    float b1[4], b2[4];
    int   k1[4];
    #pragma unroll
    for (int i = 0; i < 4; ++i) { b1[i] = 3.4e38f; b2[i] = 3.4e38f; k1[i] = 0; }

    for (int ko = 0; ko < K_CB; ko += BK) {
        float acc[4][4];
        #pragma unroll
        for (int i = 0; i < 4; ++i)
            #pragma unroll
            for (int j = 0; j < 4; ++j) acc[i][j] = 0.0f;

        for (int dc = 0; dc < D_DIM; dc += DC) {
            __syncthreads();
            #pragma unroll
            for (int it = 0; it < 2; ++it) {
                int f = it * 256 + t, col = f >> 3, d4 = f & 7;
                *reinterpret_cast<float4*>(&wt[col * WT_STRIDE + 4 * d4]) =
                    reinterpret_cast<const float4*>(w)[(size_t)(ko + col) * 64 + (dc >> 2) + d4];
            }
            __syncthreads();

            #pragma unroll
            for (int dd = 0; dd < DC; dd += 4) {
                float4 a[4], b[4];
                #pragma unroll
                for (int i = 0; i < 4; ++i)
                    a[i] = *reinterpret_cast<const float4*>(&xs[(ty * 4 + i) * D_DIM + dc + dd]);
                #pragma unroll
                for (int j = 0; j < 4; ++j)
                    b[j] = *reinterpret_cast<const float4*>(&wt[(tx + 16 * j) * WT_STRIDE + dd]);
                #pragma unroll
                for (int i = 0; i < 4; ++i)
                    #pragma unroll
                    for (int j = 0; j < 4; ++j) {
                        acc[i][j] = fmaf(a[i].x, b[j].x, acc[i][j]);
                        acc[i][j] = fmaf(a[i].y, b[j].y, acc[i][j]);
                        acc[i][j] = fmaf(a[i].z, b[j].z, acc[i][j]);
                        acc[i][j] = fmaf(a[i].w, b[j].w, acc[i][j]);
                    }
            }
        }

        #pragma unroll
        for (int j = 0; j < 4; ++j) {
            int k = ko + tx + 16 * j;
            float wsk = wsq[k];
            #pragma unroll
            for (int i = 0; i < 4; ++i) {
                float s = fmaf(-2.0f, acc[i][j], wsk);
                if (s < b1[i]) { b2[i] = b1[i]; b1[i] = s; k1[i] = k; }
                else if (s < b2[i]) b2[i] = s;
            }
        }
    }

    __syncthreads();
    float* sb1 = xs;                          // [64][16]
    float* sb2 = xs + 1024;
    int*   sk1 = reinterpret_cast<int*>(xs + 2048);
    #pragma unroll
    for (int i = 0; i < 4; ++i) {
        int r = ty * 4 + i;
        sb1[r * 16 + tx] = b1[i];
        sb2[r * 16 + tx] = b2[i];
        sk1[r * 16 + tx] = k1[i];
    }
    __syncthreads();
    if (t < BM) {
        float B1 = sb1[t * 16], B2 = sb2[t * 16];
        int   K1 = sk1[t * 16];
        #pragma unroll
        for (int c = 1; c < 16; ++c) {
            float a1 = sb1[t * 16 + c], a2 = sb2[t * 16 + c];
            int   ak = sk1[t * 16 + c];
            if (a1 < B1 || (a1 == B1 && ak < K1)) { B2 = fminf(B1, a2); B1 = a1; K1 = ak; }
            else { B2 = fminf(B2, a1); }
        }
        idx_out[r0 + t] = (float)K1;          // provisional (final for unflagged rows)
        rowmin[r0 + t]  = B1;
        if (B2 - B1 <= M_FLAG) {
            unsigned pos = atomicAdd(flag_count, 1u);
            if (pos < N_ROWS) flags[pos] = r0 + t;
        }
    }
}

// Pass 2: for flagged rows, rebuild candidate set (same fp32 math -> bit-identical scores),
// then replicate numpy's fp32-big-magnitude dist2 exactly for those candidates:
//   q = fl32( fl32(Xsq - 2*fl32(dot_exact)) + Wsq[k] ), argmin with lowest-index tie-break.
__global__ __launch_bounds__(256, 1) void fixup_kernel(
        const float* __restrict__ x, const float* __restrict__ w,
        const float* __restrict__ wsq, const float* __restrict__ xsq,
        const float* __restrict__ rowmin,
        const int* __restrict__ flags, const unsigned* __restrict__ flag_count,
        float* __restrict__ idx_out) {
    __shared__ float xs[BM * D_DIM];        // 64 KB
    __shared__ float wt[BK * WT_STRIDE];    // 9216 B
    __shared__ int   sh_rows[BM];
    __shared__ float sh_thr[BM];
    __shared__ float sh_xsq[BM];
    __shared__ int   sh_cnt[BM];
    __shared__ int   candk[BM * MAXC];      // 6144 B

    const int t  = threadIdx.x;
    const int tx = t & 15;
    const int ty = t >> 4;
    const int wave = t >> 6, lane = t & 63;

    unsigned cnt_u = flag_count[0];
    int cnt = (cnt_u > N_ROWS) ? N_ROWS : (int)cnt_u;

    for (int base = blockIdx.x * BM; base < cnt; base += gridDim.x * BM) {
        int nrows = cnt - base; if (nrows > BM) nrows = BM;

        if (t < BM) {
            int gr = flags[base + (t < nrows ? t : 0)];
            sh_rows[t] = gr;
            sh_thr[t]  = rowmin[gr] + M_CAND;
            sh_xsq[t]  = xsq[gr];
            sh_cnt[t]  = 0;
        }
        __syncthreads();

        #pragma unroll
        for (int it = 0; it < 16; ++it) {
            int f = it * 256 + t, row = f >> 6, d4 = f & 63;
            reinterpret_cast<float4*>(xs)[row * 64 + d4] =
                reinterpret_cast<const float4*>(x)[(size_t)sh_rows[row] * 64 + d4];
        }

        // GEMM sweep, collect candidates
        for (int ko = 0; ko < K_CB; ko += BK) {
            float acc[4][4];
            #pragma unroll
            for (int i = 0; i < 4; ++i)
                #pragma unroll
                for (int j = 0; j < 4; ++j) acc[i][j] = 0.0f;

            for (int dc = 0; dc < D_DIM; dc += DC) {
                __syncthreads();
                #pragma unroll
                for (int it = 0; it < 2; ++it) {
                    int f = it * 256 + t, col = f >> 3, d4 = f & 7;
                    *reinterpret_cast<float4*>(&wt[col * WT_STRIDE + 4 * d4]) =
                        reinterpret_cast<const float4*>(w)[(size_t)(ko + col) * 64 + (dc >> 2) + d4];
                }
                __syncthreads();

                #pragma unroll
                for (int dd = 0; dd < DC; dd += 4) {
                    float4 a[4], b[4];
                    #pragma unroll
                    for (int i = 0; i < 4; ++i)
                        a[i] = *reinterpret_cast<const float4*>(&xs[(ty * 4 + i) * D_DIM + dc + dd]);
                    #pragma unroll
                    for (int j = 0; j < 4; ++j)
                        b[j] = *reinterpret_cast<const float4*>(&wt[(tx + 16 * j) * WT_STRIDE + dd]);
                    #pragma unroll
                    for (int i = 0; i < 4; ++i)
                        #pragma unroll
                        for (int j = 0; j < 4; ++j) {
                            acc[i][j] = fmaf(a[i].x, b[j].x, acc[i][j]);
                            acc[i][j] = fmaf(a[i].y, b[j].y, acc[i][j]);
                            acc[i][j] = fmaf(a[i].z, b[j].z, acc[i][j]);
                            acc[i][j] = fmaf(a[i].w, b[j].w, acc[i][j]);
                        }
                }
            }

            #pragma unroll
            for (int j = 0; j < 4; ++j) {
                int k = ko + tx + 16 * j;
                float wsk = wsq[k];
                #pragma unroll
                for (int i = 0; i < 4; ++i) {
                    int r = ty * 4 + i;
                    float s = fmaf(-2.0f, acc[i][j], wsk);
                    if (r < nrows && s <= sh_thr[r]) {
                        int pos = atomicAdd(&sh_cnt[r], 1);
                        if (pos < MAXC) candk[r * MAXC + pos] = k;
                    }
                }
            }
        }
        __syncthreads();

        // fp64-exact rescore of candidates through numpy's fp32 rounding sequence
        for (int r = wave * 16; r < wave * 16 + 16; ++r) {
            if (r >= nrows) break;
            int nc = sh_cnt[r]; if (nc > MAXC) nc = MAXC;
            float bq = 3.4e38f; int bk = -1;
            for (int c = 0; c < nc; ++c) {
                int k = candk[r * MAXC + c];
                float4 xv = reinterpret_cast<float4*>(&xs[r * D_DIM])[lane];
                float4 wv = reinterpret_cast<const float4*>(w)[(size_t)k * 64 + lane];
                double d = (double)xv.x * wv.x + (double)xv.y * wv.y
                         + (double)xv.z * wv.z + (double)xv.w * wv.w;
                #pragma unroll
                for (int off = 1; off < 64; off <<= 1) d += __shfl_xor(d, off, 64);
                float XW = (float)d;                       // fl32(exact dot)
                float t3 = fmaf(-2.0f, XW, sh_xsq[r]);     // == fl32(Xsq - 2*XW), 2*XW exact
                float q  = t3 + wsq[k];                    // fl32(t3 + Wsq)
                if (q < bq || (q == bq && k < bk) || bk < 0) { bq = q; bk = k; }
            }
            if (lane == 0 && bk >= 0) idx_out[sh_rows[r]] = (float)bk;
        }
        __syncthreads();   // protect xs/lists before next outer iteration
    }
}

__global__ __launch_bounds__(256) void gather_loss_kernel(
        const float* __restrict__ x, const float* __restrict__ w,
        const float* __restrict__ idx_f, float* __restrict__ out_q,
        float* __restrict__ accum) {
    const int nf4 = Q_ELEMS / 4;
    float lsum = 0.0f;
    for (int e = blockIdx.x * blockDim.x + threadIdx.x; e < nf4;
         e += gridDim.x * blockDim.x) {
        int row = e >> 6, d4 = e & 63;
        int k = (int)idx_f[row];
        float4 xv = reinterpret_cast<const float4*>(x)[e];
        float4 qv = reinterpret_cast<const float4*>(w)[(size_t)k * 64 + d4];
        float4 ov;
        ov.x = xv.x + (qv.x - xv.x);
        ov.y = xv.y + (qv.y - xv.y);
        ov.z = xv.z + (qv.z - xv.z);
        ov.w = xv.w + (qv.w - xv.w);
        reinterpret_cast<float4*>(out_q)[e] = ov;
        float dx = xv.x - qv.x, dy = xv.y - qv.y, dz = xv.z - qv.z, dw = xv.w - qv.w;
        lsum += dx * dx + dy * dy + dz * dz + dw * dw;
    }
    #pragma unroll
    for (int off = 32; off > 0; off >>= 1) lsum += __shfl_down(lsum, off, 64);
    __shared__ float ssum[4];
    if ((threadIdx.x & 63) == 0) ssum[threadIdx.x >> 6] = lsum;
    __syncthreads();
    if (threadIdx.x == 0)
        atomicAdd(accum, ssum[0] + ssum[1] + ssum[2] + ssum[3]);
}

__global__ void finalize_kernel(const float* __restrict__ accum,
                                float* __restrict__ out_tail) {
    float mse = accum[0] / (float)Q_ELEMS;
    float commit = 0.25f * mse;
    out_tail[0] = commit;
    out_tail[1] = mse;
    out_tail[2] = commit + mse;
}

extern "C" void kernel_launch(void* const* d_in, const int* in_sizes, int n_in,
                              void* d_out, int out_size, void* d_ws, size_t ws_size,
                              hipStream_t stream) {
    const float* x = (const float*)d_in[0];
    const float* w = (const float*)d_in[1];
    float* out = (float*)d_out;

    char* ws = (char*)d_ws;
    float*    Wsq        = (float*)ws;                 // 8192 f32
    float*    Xsq        = (float*)(ws + 32768);       // 32768 f32
    float*    Rmin       = (float*)(ws + 163840);      // 32768 f32
    float*    accum      = (float*)(ws + 294912);
    unsigned* flag_count = (unsigned*)(ws + 294916);
    int*      flags      = (int*)(ws + 294920);        // 32768 i32

    hipMemsetAsync(ws + 294912, 0, 8, stream);
    sq_kernel<<<K_CB / 4, 256, 0, stream>>>(w, Wsq, K_CB);
    sq_kernel<<<N_ROWS / 4, 256, 0, stream>>>(x, Xsq, N_ROWS);
    argmin_kernel<<<N_ROWS / BM, 256, 0, stream>>>(x, w, Wsq, out + Q_ELEMS,
                                                   Rmin, flags, flag_count);
    fixup_kernel<<<96, 256, 0, stream>>>(x, w, Wsq, Xsq, Rmin, flags, flag_count,
                                         out + Q_ELEMS);
    gather_loss_kernel<<<8192, 256, 0, stream>>>(x, w, out + Q_ELEMS, out, accum);
    finalize_kernel<<<1, 1, 0, stream>>>(accum, out + Q_ELEMS + N_ROWS);
}

// Round 4
// 712.415 us; speedup vs baseline: 8.1039x; 8.1039x over previous
//
#include <hip/hip_runtime.h>

#define K_CB   8192
#define D_DIM  256
#define N_ROWS 32768
#define Q_ELEMS (N_ROWS * D_DIM)

#define RSU    264        // LDS row stride in ushorts (256 + 8 pad -> 2-way banks, 16B aligned)
#define M_FLAG 1.0e-4f    // np-quant 6.1e-5 + 2x bf16 score err 1.5e-5, rounded up
#define M_CAND 1.0e-4f
#define CAP    32

typedef __bf16 bf16x8 __attribute__((ext_vector_type(8)));
typedef float  f32x4  __attribute__((ext_vector_type(4)));

// ws layout (bytes):
//   0       Wsq     [8192 f32]
//   32768   Xsq     [32768 f32]
//   163840  rowmin  [32768 f32]
//   294912  accum f32 | 294916 flag_count u32   (memset 8B)
//   294920  flags   [32768 i32]
//   425992  candcnt [32768 i32]
//   557064  cands   [32768*32 i32]
//   4751368 pb1 [2*32768 f32] | 5013512 pb2 | 5275656 pk1 (i32)
//   5537808 Wbf     [8192*256 ushort]   (16B aligned)
// total ~9.3 MB

__device__ inline ushort f2bf(float f) {          // RNE float->bf16
    unsigned u = __float_as_uint(f);
    unsigned r = u + 0x7FFFu + ((u >> 16) & 1u);
    return (ushort)(r >> 16);
}

// fp32-rounded fp64 sum of squares per 256-float row (np w_sq / x_sq replication, verified R3)
__global__ void sq_kernel(const float* __restrict__ m, float* __restrict__ out, int rows) {
    int wave = threadIdx.x >> 6, lane = threadIdx.x & 63;
    int row = blockIdx.x * 4 + wave;
    if (row >= rows) return;
    float4 v = reinterpret_cast<const float4*>(m)[(size_t)row * 64 + lane];
    double s = (double)v.x * v.x + (double)v.y * v.y + (double)v.z * v.z + (double)v.w * v.w;
    #pragma unroll
    for (int off = 32; off > 0; off >>= 1) s += __shfl_down(s, off, 64);
    if (lane == 0) out[row] = (float)s;
}

// W fp32 -> bf16 (RNE), 4 elems/thread
__global__ void wbf_kernel(const float* __restrict__ w, ushort* __restrict__ wbf) {
    int e = blockIdx.x * 256 + threadIdx.x;        // float4 index, 2048*256 = K_CB*D/4
    float4 v = reinterpret_cast<const float4*>(w)[e];
    uint2 o;
    o.x = (uint)f2bf(v.x) | ((uint)f2bf(v.y) << 16);
    o.y = (uint)f2bf(v.z) | ((uint)f2bf(v.w) << 16);
    reinterpret_cast<uint2*>(wbf)[e] = o;
}

// Pass 1: bf16 MFMA GEMM-argmin, 64 rows x 4096 cols per block (k-split=2)
__global__ __launch_bounds__(256, 2) void argmin_mfma_kernel(
        const float* __restrict__ x, const ushort* __restrict__ wbf,
        const float* __restrict__ wsq,
        float* __restrict__ pb1, float* __restrict__ pb2, int* __restrict__ pk1) {
    __shared__ __align__(16) ushort xs[64 * RSU];   // 33792 B
    __shared__ __align__(16) ushort wt[64 * RSU];   // 33792 B (reused for merge)

    const int t    = threadIdx.x;
    const int lane = t & 63, wv = t >> 6;
    const int g    = blockIdx.x >> 1, split = blockIdx.x & 1;
    const int r0   = g * 64;
    const int k0   = split * (K_CB / 2);
    const int m    = lane & 15, q = lane >> 4;

    // stage xs (fp32 -> bf16): 16B slots, slot = s*256+t -> n=slot>>5, c=slot&31
    #pragma unroll
    for (int s = 0; s < 8; ++s) {
        int slot = s * 256 + t, n = slot >> 5, c = slot & 31;
        const float4* src = reinterpret_cast<const float4*>(x) + (size_t)(r0 + n) * 64 + c * 2;
        float4 f0 = src[0], f1 = src[1];
        uint4 o;
        o.x = (uint)f2bf(f0.x) | ((uint)f2bf(f0.y) << 16);
        o.y = (uint)f2bf(f0.z) | ((uint)f2bf(f0.w) << 16);
        o.z = (uint)f2bf(f1.x) | ((uint)f2bf(f1.y) << 16);
        o.w = (uint)f2bf(f1.z) | ((uint)f2bf(f1.w) << 16);
        *reinterpret_cast<uint4*>(&xs[n * RSU + c * 8]) = o;
    }

    float b1[4], b2[4]; int k1[4];
    #pragma unroll
    for (int r = 0; r < 4; ++r) { b1[r] = 3.4e38f; b2[r] = 3.4e38f; k1[r] = 0; }

    const int arow = (16 * wv + m) * RSU + q * 8;

    for (int kc = 0; kc < K_CB / 2; kc += 64) {
        __syncthreads();   // wt reuse (also covers xs staging first pass)
        #pragma unroll
        for (int s = 0; s < 8; ++s) {
            int slot = s * 256 + t, n = slot >> 5, c = slot & 31;
            *reinterpret_cast<uint4*>(&wt[n * RSU + c * 8]) =
                *reinterpret_cast<const uint4*>(&wbf[(size_t)(k0 + kc + n) * 256 + c * 8]);
        }
        __syncthreads();

        f32x4 acc[4] = {{0,0,0,0},{0,0,0,0},{0,0,0,0},{0,0,0,0}};
        #pragma unroll
        for (int kk = 0; kk < 8; ++kk) {
            bf16x8 a = *reinterpret_cast<const bf16x8*>(&xs[arow + kk * 32]);
            #pragma unroll
            for (int j = 0; j < 4; ++j) {
                bf16x8 b = *reinterpret_cast<const bf16x8*>(&wt[(16 * j + m) * RSU + q * 8 + kk * 32]);
                acc[j] = __builtin_amdgcn_mfma_f32_16x16x32_bf16(a, b, acc[j], 0, 0, 0);
            }
        }
        #pragma unroll
        for (int j = 0; j < 4; ++j) {
            int k = k0 + kc + 16 * j + m;           // ascending within lane -> lowest-k ties
            float wsk = wsq[k];
            #pragma unroll
            for (int r = 0; r < 4; ++r) {
                float s = fmaf(-2.0f, acc[j][r], wsk);
                if (s < b1[r]) { b2[r] = b1[r]; b1[r] = s; k1[r] = k; }
                else if (s < b2[r]) b2[r] = s;
            }
        }
    }

    // per-row merge across the 16 col-lanes; C/D row = q*4+r within wave's 16-row strip
    __syncthreads();
    float* mb1 = reinterpret_cast<float*>(wt);
    float* mb2 = mb1 + 1024;
    int*   mk1 = reinterpret_cast<int*>(mb2 + 1024);
    #pragma unroll
    for (int r = 0; r < 4; ++r) {
        int row = 16 * wv + q * 4 + r;
        mb1[row * 16 + m] = b1[r];
        mb2[row * 16 + m] = b2[r];
        mk1[row * 16 + m] = k1[r];
    }
    __syncthreads();
    if (t < 64) {
        float B1 = mb1[t * 16], B2 = mb2[t * 16];
        int   K1 = mk1[t * 16];
        #pragma unroll
        for (int c = 1; c < 16; ++c) {
            float a1 = mb1[t * 16 + c], a2 = mb2[t * 16 + c];
            int   ak = mk1[t * 16 + c];
            if (a1 < B1 || (a1 == B1 && ak < K1)) { B2 = fminf(B1, a2); B1 = a1; K1 = ak; }
            else { B2 = fminf(B2, a1); }
        }
        int p = split * N_ROWS + r0 + t;
        pb1[p] = B1; pb2[p] = B2; pk1[p] = K1;
    }
}

// merge the 2 k-split partials, write provisional idx, rowmin, flags; zero candcnt
__global__ __launch_bounds__(256) void merge_kernel(
        const float* __restrict__ pb1, const float* __restrict__ pb2,
        const int* __restrict__ pk1, float* __restrict__ idx_out,
        float* __restrict__ rowmin, int* __restrict__ flags,
        unsigned* __restrict__ flag_count, int* __restrict__ candcnt) {
    int row = blockIdx.x * 256 + threadIdx.x;
    float B1 = pb1[row], B2 = pb2[row];
    int   K1 = pk1[row];
    float a1 = pb1[N_ROWS + row], a2 = pb2[N_ROWS + row];
    int   ak = pk1[N_ROWS + row];
    if (a1 < B1) { B2 = fminf(B1, a2); B1 = a1; K1 = ak; }   // a1==B1: keep lower-k split0
    else         { B2 = fminf(B2, a1); }
    idx_out[row] = (float)K1;
    rowmin[row]  = B1;
    candcnt[row] = 0;
    if (B2 - B1 <= M_FLAG) {
        unsigned pos = atomicAdd(flag_count, 1u);
        if (pos < N_ROWS) flags[pos] = row;
    }
}

// fixup sweep: same MFMA math over gathered flagged rows; append candidates <= rowmin+M_CAND
__global__ __launch_bounds__(256, 2) void fixup_mfma_kernel(
        const float* __restrict__ x, const ushort* __restrict__ wbf,
        const float* __restrict__ wsq, const float* __restrict__ rowmin,
        const int* __restrict__ flags, const unsigned* __restrict__ flag_count,
        int* __restrict__ candcnt, int* __restrict__ cands) {
    __shared__ __align__(16) ushort xs[64 * RSU];
    __shared__ __align__(16) ushort wt[64 * RSU];
    __shared__ int   sh_rows[64];
    __shared__ float sh_thr[64];

    const int t    = threadIdx.x;
    const int lane = t & 63, wv = t >> 6;
    const int m    = lane & 15, q = lane >> 4;
    const int g    = blockIdx.x >> 1, half = blockIdx.x & 1;
    const int k0   = half * (K_CB / 2);

    unsigned cu = flag_count[0];
    int cnt = (cu > N_ROWS) ? N_ROWS : (int)cu;

    for (int grp = g; grp * 64 < cnt; grp += 256) {
        int base = grp * 64;
        int nrows = cnt - base; if (nrows > 64) nrows = 64;

        __syncthreads();   // protect xs/wt/sh from previous iteration
        if (t < 64) {
            int gr = flags[base + (t < nrows ? t : 0)];
            sh_rows[t] = gr;
            sh_thr[t]  = rowmin[gr] + M_CAND;
        }
        __syncthreads();

        #pragma unroll
        for (int s = 0; s < 8; ++s) {
            int slot = s * 256 + t, n = slot >> 5, c = slot & 31;
            const float4* src = reinterpret_cast<const float4*>(x) + (size_t)sh_rows[n] * 64 + c * 2;
            float4 f0 = src[0], f1 = src[1];
            uint4 o;
            o.x = (uint)f2bf(f0.x) | ((uint)f2bf(f0.y) << 16);
            o.y = (uint)f2bf(f0.z) | ((uint)f2bf(f0.w) << 16);
            o.z = (uint)f2bf(f1.x) | ((uint)f2bf(f1.y) << 16);
            o.w = (uint)f2bf(f1.z) | ((uint)f2bf(f1.w) << 16);
            *reinterpret_cast<uint4*>(&xs[n * RSU + c * 8]) = o;
        }

        float thr_r[4]; int grow_r[4], rloc[4];
        const int arow = (16 * wv + m) * RSU + q * 8;

        for (int kc = 0; kc < K_CB / 2; kc += 64) {
            __syncthreads();
            #pragma unroll
            for (int s = 0; s < 8; ++s) {
                int slot = s * 256 + t, n = slot >> 5, c = slot & 31;
                *reinterpret_cast<uint4*>(&wt[n * RSU + c * 8]) =
                    *reinterpret_cast<const uint4*>(&wbf[(size_t)(k0 + kc + n) * 256 + c * 8]);
            }
            __syncthreads();
            if (kc == 0) {
                #pragma unroll
                for (int r = 0; r < 4; ++r) {
                    rloc[r]   = 16 * wv + q * 4 + r;
                    thr_r[r]  = sh_thr[rloc[r]];
                    grow_r[r] = sh_rows[rloc[r]];
                }
            }

            f32x4 acc[4] = {{0,0,0,0},{0,0,0,0},{0,0,0,0},{0,0,0,0}};
            #pragma unroll
            for (int kk = 0; kk < 8; ++kk) {
                bf16x8 a = *reinterpret_cast<const bf16x8*>(&xs[arow + kk * 32]);
                #pragma unroll
                for (int j = 0; j < 4; ++j) {
                    bf16x8 b = *reinterpret_cast<const bf16x8*>(&wt[(16 * j + m) * RSU + q * 8 + kk * 32]);
                    acc[j] = __builtin_amdgcn_mfma_f32_16x16x32_bf16(a, b, acc[j], 0, 0, 0);
                }
            }
            #pragma unroll
            for (int j = 0; j < 4; ++j) {
                int k = k0 + kc + 16 * j + m;
                float wsk = wsq[k];
                #pragma unroll
                for (int r = 0; r < 4; ++r) {
                    float s = fmaf(-2.0f, acc[j][r], wsk);
                    if (rloc[r] < nrows && s <= thr_r[r]) {
                        int row = grow_r[r];
                        int pos = atomicAdd(&candcnt[row], 1);
                        if (pos < CAP) cands[row * CAP + pos] = k;
                    }
                }
            }
        }
    }
}

// np-exact rescore of candidates (verified R3 math): q = fl32(fl32(Xsq-2*fl32(dot)) + Wsq)
__global__ __launch_bounds__(256) void rescore_kernel(
        const float* __restrict__ x, const float* __restrict__ w,
        const float* __restrict__ wsq, const float* __restrict__ xsq,
        const int* __restrict__ flags, const unsigned* __restrict__ flag_count,
        const int* __restrict__ candcnt, const int* __restrict__ cands,
        float* __restrict__ idx_out) {
    int wid  = (blockIdx.x * 256 + threadIdx.x) >> 6;   // 1024 waves
    int lane = threadIdx.x & 63;
    unsigned cu = flag_count[0];
    int cnt = (cu > N_ROWS) ? N_ROWS : (int)cu;

    for (int fi = wid; fi < cnt; fi += 1024) {
        int row = flags[fi];
        float4 xv = reinterpret_cast<const float4*>(x)[(size_t)row * 64 + lane];
        float Xs = xsq[row];
        int nc = candcnt[row]; if (nc > CAP) nc = CAP;
        float bq = 3.4e38f; int bk = -1;
        for (int c = 0; c < nc; ++c) {
            int k = cands[row * CAP + c];
            float4 wv = reinterpret_cast<const float4*>(w)[(size_t)k * 64 + lane];
            double d = (double)xv.x * wv.x + (double)xv.y * wv.y
                     + (double)xv.z * wv.z + (double)xv.w * wv.w;
            #pragma unroll
            for (int off = 1; off < 64; off <<= 1) d += __shfl_xor(d, off, 64);
            float XW = (float)d;
            float t3 = fmaf(-2.0f, XW, Xs);
            float qv = t3 + wsq[k];
            if (qv < bq || (qv == bq && k < bk) || bk < 0) { bq = qv; bk = k; }
        }
        if (lane == 0 && bk >= 0) idx_out[row] = (float)bk;
    }
}

__global__ __launch_bounds__(256) void gather_loss_kernel(
        const float* __restrict__ x, const float* __restrict__ w,
        const float* __restrict__ idx_f, float* __restrict__ out_q,
        float* __restrict__ accum) {
    const int nf4 = Q_ELEMS / 4;
    float lsum = 0.0f;
    for (int e = blockIdx.x * blockDim.x + threadIdx.x; e < nf4;
         e += gridDim.x * blockDim.x) {
        int row = e >> 6, d4 = e & 63;
        int k = (int)idx_f[row];
        float4 xv = reinterpret_cast<const float4*>(x)[e];
        float4 qv = reinterpret_cast<const float4*>(w)[(size_t)k * 64 + d4];
        float4 ov;
        ov.x = xv.x + (qv.x - xv.x);
        ov.y = xv.y + (qv.y - xv.y);
        ov.z = xv.z + (qv.z - xv.z);
        ov.w = xv.w + (qv.w - xv.w);
        reinterpret_cast<float4*>(out_q)[e] = ov;
        float dx = xv.x - qv.x, dy = xv.y - qv.y, dz = xv.z - qv.z, dw = xv.w - qv.w;
        lsum += dx * dx + dy * dy + dz * dz + dw * dw;
    }
    #pragma unroll
    for (int off = 32; off > 0; off >>= 1) lsum += __shfl_down(lsum, off, 64);
    __shared__ float ssum[4];
    if ((threadIdx.x & 63) == 0) ssum[threadIdx.x >> 6] = lsum;
    __syncthreads();
    if (threadIdx.x == 0)
        atomicAdd(accum, ssum[0] + ssum[1] + ssum[2] + ssum[3]);
}

__global__ void finalize_kernel(const float* __restrict__ accum,
                                float* __restrict__ out_tail) {
    float mse = accum[0] / (float)Q_ELEMS;
    float commit = 0.25f * mse;
    out_tail[0] = commit;
    out_tail[1] = mse;
    out_tail[2] = commit + mse;
}

extern "C" void kernel_launch(void* const* d_in, const int* in_sizes, int n_in,
                              void* d_out, int out_size, void* d_ws, size_t ws_size,
                              hipStream_t stream) {
    const float* x = (const float*)d_in[0];
    const float* w = (const float*)d_in[1];
    float* out = (float*)d_out;

    char* ws = (char*)d_ws;
    float*    Wsq        = (float*)ws;
    float*    Xsq        = (float*)(ws + 32768);
    float*    Rmin       = (float*)(ws + 163840);
    float*    accum      = (float*)(ws + 294912);
    unsigned* flag_count = (unsigned*)(ws + 294916);
    int*      flags      = (int*)(ws + 294920);
    int*      candcnt    = (int*)(ws + 425992);
    int*      cands      = (int*)(ws + 557064);
    float*    pb1        = (float*)(ws + 4751368);
    float*    pb2        = (float*)(ws + 5013512);
    int*      pk1        = (int*)(ws + 5275656);
    ushort*   Wbf        = (ushort*)(ws + 5537808);

    hipMemsetAsync(ws + 294912, 0, 8, stream);  // accum + flag_count
    sq_kernel<<<K_CB / 4, 256, 0, stream>>>(w, Wsq, K_CB);
    sq_kernel<<<N_ROWS / 4, 256, 0, stream>>>(x, Xsq, N_ROWS);
    wbf_kernel<<<K_CB * D_DIM / 1024, 256, 0, stream>>>(w, Wbf);
    argmin_mfma_kernel<<<(N_ROWS / 64) * 2, 256, 0, stream>>>(x, Wbf, Wsq, pb1, pb2, pk1);
    merge_kernel<<<N_ROWS / 256, 256, 0, stream>>>(pb1, pb2, pk1, out + Q_ELEMS,
                                                   Rmin, flags, flag_count, candcnt);
    fixup_mfma_kernel<<<512, 256, 0, stream>>>(x, Wbf, Wsq, Rmin, flags, flag_count,
                                               candcnt, cands);
    rescore_kernel<<<256, 256, 0, stream>>>(x, w, Wsq, Xsq, flags, flag_count,
                                            candcnt, cands, out + Q_ELEMS);
    gather_loss_kernel<<<8192, 256, 0, stream>>>(x, w, out + Q_ELEMS, out, accum);
    finalize_kernel<<<1, 1, 0, stream>>>(accum, out + Q_ELEMS + N_ROWS);
}